// Round 1
// baseline (385.275 us; speedup 1.0000x reference)
//
#include <hip/hip_runtime.h>

typedef unsigned short u16;
typedef short s16x8 __attribute__((ext_vector_type(8)));
typedef float f32x4 __attribute__((ext_vector_type(4)));
typedef float f32x2 __attribute__((ext_vector_type(2)));

#define NNODES 55296
#define NEDGES 221184
#define ROWS   110592   // B * NNODES

__device__ __forceinline__ u16 f2bf(float f) {
    union { float f; unsigned u; } v; v.f = f;
    unsigned r = (v.u + 0x7fffu + ((v.u >> 16) & 1u)) >> 16;
    return (u16)r;
}
__device__ __forceinline__ float bf2f(u16 u) {
    return __uint_as_float(((unsigned)u) << 16);
}

// ---------------------------------------------------------------------------
// Pack a [32 x ncols] fp32 matrix (optionally transposed source [ncols x 32])
// into MFMA B-fragment layout: frag[t][lane][j] = B[k=quad*8+j][n=t*16+(lane&15)]
// Writes hi (bf16 RNE) and optionally lo (residual) buffers.
// ---------------------------------------------------------------------------
__global__ __launch_bounds__(256) void pack_bfrag(
    const float* __restrict__ src, u16* __restrict__ dst_hi, u16* __restrict__ dst_lo,
    int ntiles, int ncols, int trans)
{
    int idx = blockIdx.x * 256 + threadIdx.x;
    if (idx >= ntiles * 512) return;
    int t = idx >> 9, rr = idx & 511, lane = rr >> 3, j = rr & 7;
    int k = (lane >> 4) * 8 + j;
    int n = t * 16 + (lane & 15);
    float v = trans ? src[n * 32 + k] : src[k * ncols + n];
    u16 hb = f2bf(v);
    dst_hi[idx] = hb;
    if (dst_lo) dst_lo[idx] = f2bf(v - bf2f(hb));
}

// ---------------------------------------------------------------------------
// Edge MLP layer 1: r[e,o] = relu(er[e,:4] @ ew1 + eb1) -> bf16 (A-operand rows)
// ---------------------------------------------------------------------------
__global__ __launch_bounds__(256) void edgemlp_kernel(
    const float* __restrict__ er, const float* __restrict__ ew1,
    const float* __restrict__ eb1, u16* __restrict__ rbf)
{
    __shared__ float er_lds[32];
    __shared__ float w_lds[128];
    __shared__ float b_lds[32];
    int tid = threadIdx.x;
    int e8 = blockIdx.x * 8;
    if (tid < 32) er_lds[tid] = er[e8 * 4 + tid];
    else if (tid < 160) w_lds[tid - 32] = ew1[tid - 32];
    else if (tid < 192) b_lds[tid - 160] = eb1[tid - 160];
    __syncthreads();
    int el = tid >> 5, o = tid & 31;
    const float* e4 = er_lds + el * 4;
    float v = b_lds[o] + e4[0] * w_lds[o] + e4[1] * w_lds[32 + o]
                       + e4[2] * w_lds[64 + o] + e4[3] * w_lds[96 + o];
    rbf[(e8 + el) * 32 + o] = f2bf(fmaxf(v, 0.f));
}

// ---------------------------------------------------------------------------
// Node projection: h0 = relu(x@pw1+pb1)@pw2+pb2, 3-term bf16-split MFMA.
// One wave per 16 rows. Writes state fp32 + hi/lo bf16.
// ---------------------------------------------------------------------------
__global__ __launch_bounds__(256) void nodeproj_kernel(
    const float* __restrict__ x,
    const u16* __restrict__ pw1h, const u16* __restrict__ pw1l, const float* __restrict__ pb1,
    const u16* __restrict__ pw2h, const u16* __restrict__ pw2l, const float* __restrict__ pb2,
    float* __restrict__ st_f32, u16* __restrict__ st_hi, u16* __restrict__ st_lo)
{
    __shared__ alignas(16) u16 t_hi[4][512];
    __shared__ alignas(16) u16 t_lo[4][512];
    int tid = threadIdx.x, wave = tid >> 6, lane = tid & 63;
    int quad = lane >> 4, col = lane & 15;
    int row0 = (blockIdx.x * 4 + wave) * 16;

    const float* xp = x + (row0 + col) * 32 + quad * 8;
    f32x4 xv0 = *(const f32x4*)(xp), xv1 = *(const f32x4*)(xp + 4);
    s16x8 ah, al;
#pragma unroll
    for (int i = 0; i < 4; ++i) {
        u16 h0 = f2bf(xv0[i]); ah[i] = (short)h0; al[i] = (short)f2bf(xv0[i] - bf2f(h0));
        u16 h1 = f2bf(xv1[i]); ah[4+i] = (short)h1; al[4+i] = (short)f2bf(xv1[i] - bf2f(h1));
    }
#pragma unroll
    for (int t = 0; t < 2; ++t) {
        s16x8 bh = *(const s16x8*)(pw1h + t * 512 + lane * 8);
        s16x8 bl = *(const s16x8*)(pw1l + t * 512 + lane * 8);
        f32x4 acc = {0,0,0,0};
        acc = __builtin_amdgcn_mfma_f32_16x16x32_bf16(al, bh, acc, 0,0,0);
        acc = __builtin_amdgcn_mfma_f32_16x16x32_bf16(ah, bl, acc, 0,0,0);
        acc = __builtin_amdgcn_mfma_f32_16x16x32_bf16(ah, bh, acc, 0,0,0);
        float bias = pb1[t * 16 + col];
#pragma unroll
        for (int r = 0; r < 4; ++r) {
            float v = fmaxf(acc[r] + bias, 0.f);
            u16 hb = f2bf(v);
            int idx = (quad * 4 + r) * 32 + t * 16 + col;
            t_hi[wave][idx] = hb;
            t_lo[wave][idx] = f2bf(v - bf2f(hb));
        }
    }
    __syncthreads();
    s16x8 th = *(const s16x8*)(&t_hi[wave][col * 32 + quad * 8]);
    s16x8 tl = *(const s16x8*)(&t_lo[wave][col * 32 + quad * 8]);
#pragma unroll
    for (int t = 0; t < 2; ++t) {
        s16x8 bh = *(const s16x8*)(pw2h + t * 512 + lane * 8);
        s16x8 bl = *(const s16x8*)(pw2l + t * 512 + lane * 8);
        f32x4 acc = {0,0,0,0};
        acc = __builtin_amdgcn_mfma_f32_16x16x32_bf16(tl, bh, acc, 0,0,0);
        acc = __builtin_amdgcn_mfma_f32_16x16x32_bf16(th, bl, acc, 0,0,0);
        acc = __builtin_amdgcn_mfma_f32_16x16x32_bf16(th, bh, acc, 0,0,0);
        float bias = pb2[t * 16 + col];
#pragma unroll
        for (int r = 0; r < 4; ++r) {
            float v = acc[r] + bias;
            int row = row0 + quad * 4 + r;
            int o = t * 16 + col;
            st_f32[row * 32 + o] = v;
            u16 hb = f2bf(v);
            st_hi[row * 32 + o] = hb;
            st_lo[row * 32 + o] = f2bf(v - bf2f(hb));
        }
    }
}

// ---------------------------------------------------------------------------
// Message + scatter kernel. One wave per 16 edges (block = 64 edges).
// We[e, h*32+o] computed on the fly via MFMA (K=32); epilogue fuses the
// per-edge matvec with gathered node features and atomic-scatters to agg.
// ---------------------------------------------------------------------------
__global__ __launch_bounds__(256) void msg_kernel(
    const u16* __restrict__ rbf, const u16* __restrict__ ew2f,
    const float* __restrict__ eb2, const float* __restrict__ state,
    const int* __restrict__ esrc, const int* __restrict__ edst,
    float* __restrict__ agg)
{
    __shared__ alignas(16) float eb2_lds[1024];
    __shared__ alignas(16) float ns_lds[4][16 * 68];   // [wave][e*68 + b*32 + h]
    int tid = threadIdx.x;
    {   // stage eb2 (block-wide)
        *(f32x4*)(eb2_lds + tid * 4) = *(const f32x4*)(eb2 + tid * 4);
    }
    int wave = tid >> 6, lane = tid & 63;
    int quad = lane >> 4, col = lane & 15;
    int e0 = (blockIdx.x * 4 + wave) * 16;

    // A fragment: r rows (16 edges x K=32)
    s16x8 afrag = *(const s16x8*)(rbf + (e0 + col) * 32 + quad * 8);

    // stage gathered node features: ns[e][b][h], e-stride 68 (16B-aligned, bank-safe)
    {
        int el = lane >> 2, part = lane & 3;
        int b = part >> 1, half = part & 1;
        int src = esrc[e0 + el];
        const float* sp = state + (b * NNODES + src) * 32 + half * 16;
        float* dp = &ns_lds[wave][el * 68 + b * 32 + half * 16];
        *(f32x4*)(dp + 0)  = *(const f32x4*)(sp + 0);
        *(f32x4*)(dp + 4)  = *(const f32x4*)(sp + 4);
        *(f32x4*)(dp + 8)  = *(const f32x4*)(sp + 8);
        *(f32x4*)(dp + 12) = *(const f32x4*)(sp + 12);
    }
    int dstid[4];
#pragma unroll
    for (int r = 0; r < 4; ++r) dstid[r] = edst[e0 + quad * 4 + r];
    __syncthreads();

    float msg[2][2][4] = {};   // [b][o-half][reg]
    const float* nsw = &ns_lds[wave][0];
#pragma unroll 4
    for (int hh = 0; hh < 16; ++hh) {
        int h0 = hh * 2, h1 = hh * 2 + 1;
        s16x8 b0 = *(const s16x8*)(ew2f + (4 * hh + 0) * 512 + lane * 8);
        s16x8 b1 = *(const s16x8*)(ew2f + (4 * hh + 1) * 512 + lane * 8);
        s16x8 b2 = *(const s16x8*)(ew2f + (4 * hh + 2) * 512 + lane * 8);
        s16x8 b3 = *(const s16x8*)(ew2f + (4 * hh + 3) * 512 + lane * 8);
        f32x4 z = {0,0,0,0};
        f32x4 d0 = __builtin_amdgcn_mfma_f32_16x16x32_bf16(afrag, b0, z, 0,0,0);
        f32x4 d1 = __builtin_amdgcn_mfma_f32_16x16x32_bf16(afrag, b1, z, 0,0,0);
        f32x4 d2 = __builtin_amdgcn_mfma_f32_16x16x32_bf16(afrag, b2, z, 0,0,0);
        f32x4 d3 = __builtin_amdgcn_mfma_f32_16x16x32_bf16(afrag, b3, z, 0,0,0);
        float e00 = eb2_lds[h0 * 32 + col],      e01 = eb2_lds[h0 * 32 + 16 + col];
        float e10 = eb2_lds[h1 * 32 + col],      e11 = eb2_lds[h1 * 32 + 16 + col];
#pragma unroll
        for (int r = 0; r < 4; ++r) {
            int e = quad * 4 + r;
            f32x2 n0 = *(const f32x2*)(nsw + e * 68 + 0 * 32 + h0);  // b=0: h0,h1
            f32x2 n1 = *(const f32x2*)(nsw + e * 68 + 1 * 32 + h0);  // b=1
            float w00 = d0[r] + e00, w01 = d1[r] + e01;
            float w10 = d2[r] + e10, w11 = d3[r] + e11;
            msg[0][0][r] += n0.x * w00 + n0.y * w10;
            msg[0][1][r] += n0.x * w01 + n0.y * w11;
            msg[1][0][r] += n1.x * w00 + n1.y * w10;
            msg[1][1][r] += n1.x * w01 + n1.y * w11;
        }
    }
#pragma unroll
    for (int r = 0; r < 4; ++r) {
#pragma unroll
        for (int b = 0; b < 2; ++b) {
            float* base = agg + (b * NNODES + dstid[r]) * 32;
            unsafeAtomicAdd(base + col,      msg[b][0][r]);
            unsafeAtomicAdd(base + 16 + col, msg[b][1][r]);
        }
    }
}

// ---------------------------------------------------------------------------
// GRU step. node = relu(agg + conv_b) built in-register; gx/gh via 3-term
// bf16-split MFMA; gates + state update in fp32. One wave per 16 rows.
// ---------------------------------------------------------------------------
__global__ __launch_bounds__(256) void gru_kernel(
    const float* __restrict__ agg, const float* __restrict__ conv_b,
    const float* __restrict__ st_f32, const u16* __restrict__ st_hi, const u16* __restrict__ st_lo,
    const u16* __restrict__ wihh, const u16* __restrict__ wihl,
    const u16* __restrict__ whhh, const u16* __restrict__ whhl,
    const float* __restrict__ b_ih, const float* __restrict__ b_hh,
    float* __restrict__ out_f32, u16* __restrict__ out_hi, u16* __restrict__ out_lo)
{
    int tid = threadIdx.x, wave = tid >> 6, lane = tid & 63;
    int quad = lane >> 4, col = lane & 15;
    int row0 = (blockIdx.x * 4 + wave) * 16;

    const float* ap = agg + (row0 + col) * 32 + quad * 8;
    f32x4 av0 = *(const f32x4*)(ap), av1 = *(const f32x4*)(ap + 4);
    const float* cb = conv_b + quad * 8;
    f32x4 cb0 = *(const f32x4*)(cb), cb1 = *(const f32x4*)(cb + 4);
    s16x8 anh, anl;
#pragma unroll
    for (int i = 0; i < 4; ++i) {
        float v0 = fmaxf(av0[i] + cb0[i], 0.f);
        float v1 = fmaxf(av1[i] + cb1[i], 0.f);
        u16 h0 = f2bf(v0); anh[i] = (short)h0;   anl[i] = (short)f2bf(v0 - bf2f(h0));
        u16 h1 = f2bf(v1); anh[4+i] = (short)h1; anl[4+i] = (short)f2bf(v1 - bf2f(h1));
    }
    s16x8 ahh = *(const s16x8*)(st_hi + (row0 + col) * 32 + quad * 8);
    s16x8 ahl = *(const s16x8*)(st_lo + (row0 + col) * 32 + quad * 8);

    f32x4 gx[6], gh[6];
#pragma unroll
    for (int t = 0; t < 6; ++t) {
        s16x8 bh = *(const s16x8*)(wihh + t * 512 + lane * 8);
        s16x8 bl = *(const s16x8*)(wihl + t * 512 + lane * 8);
        f32x4 acc = {0,0,0,0};
        acc = __builtin_amdgcn_mfma_f32_16x16x32_bf16(anl, bh, acc, 0,0,0);
        acc = __builtin_amdgcn_mfma_f32_16x16x32_bf16(anh, bl, acc, 0,0,0);
        acc = __builtin_amdgcn_mfma_f32_16x16x32_bf16(anh, bh, acc, 0,0,0);
        gx[t] = acc;
        s16x8 ch = *(const s16x8*)(whhh + t * 512 + lane * 8);
        s16x8 cl = *(const s16x8*)(whhl + t * 512 + lane * 8);
        f32x4 acc2 = {0,0,0,0};
        acc2 = __builtin_amdgcn_mfma_f32_16x16x32_bf16(ahl, ch, acc2, 0,0,0);
        acc2 = __builtin_amdgcn_mfma_f32_16x16x32_bf16(ahh, cl, acc2, 0,0,0);
        acc2 = __builtin_amdgcn_mfma_f32_16x16x32_bf16(ahh, ch, acc2, 0,0,0);
        gh[t] = acc2;
    }
    float bihv[6], bhhv[6];
#pragma unroll
    for (int t = 0; t < 6; ++t) { bihv[t] = b_ih[t * 16 + col]; bhhv[t] = b_hh[t * 16 + col]; }

#pragma unroll
    for (int r = 0; r < 4; ++r) {
        int row = row0 + quad * 4 + r;
#pragma unroll
        for (int oh = 0; oh < 2; ++oh) {
            int o = oh * 16 + col;
            float hid = st_f32[row * 32 + o];
            float sr = (gx[oh][r] + bihv[oh]) + (gh[oh][r] + bhhv[oh]);
            float sz = (gx[2+oh][r] + bihv[2+oh]) + (gh[2+oh][r] + bhhv[2+oh]);
            float gxn = gx[4+oh][r] + bihv[4+oh];
            float ghn = gh[4+oh][r] + bhhv[4+oh];
            float rr = 1.f / (1.f + __expf(-sr));
            float zz = 1.f / (1.f + __expf(-sz));
            float narg = gxn + rr * ghn;
            float ex = __expf(2.f * narg);
            float nn = (ex - 1.f) / (ex + 1.f);
            float hnew = (1.f - zz) * nn + zz * hid;
            out_f32[row * 32 + o] = hnew;
            u16 hb = f2bf(hnew);
            out_hi[row * 32 + o] = hb;
            out_lo[row * 32 + o] = f2bf(hnew - bf2f(hb));
        }
    }
}

// ---------------------------------------------------------------------------
extern "C" void kernel_launch(void* const* d_in, const int* in_sizes, int n_in,
                              void* d_out, int out_size, void* d_ws, size_t ws_size,
                              hipStream_t stream)
{
    const float* x      = (const float*)d_in[0];
    const float* er     = (const float*)d_in[1];
    const float* pw1    = (const float*)d_in[2];
    const float* pb1    = (const float*)d_in[3];
    const float* pw2    = (const float*)d_in[4];
    const float* pb2    = (const float*)d_in[5];
    const float* ew1    = (const float*)d_in[6];
    const float* eb1    = (const float*)d_in[7];
    const float* ew2    = (const float*)d_in[8];
    const float* eb2    = (const float*)d_in[9];
    const float* conv_b = (const float*)d_in[10];
    const float* wih    = (const float*)d_in[11];
    const float* whh    = (const float*)d_in[12];
    const float* bih    = (const float*)d_in[13];
    const float* bhh    = (const float*)d_in[14];
    const int*   esrc   = (const int*)d_in[15];
    const int*   edst   = (const int*)d_in[16];
    float* out = (float*)d_out;

    char* ws = (char*)d_ws;
    size_t off = 0;
    auto alloc = [&](size_t bytes) -> void* {
        void* p = ws + off;
        off = (off + bytes + 255) & ~(size_t)255;
        return p;
    };
    u16*   rbf    = (u16*)  alloc((size_t)NEDGES * 32 * 2);
    float* st_f32 = (float*)alloc((size_t)ROWS * 32 * 4);
    u16*   st_hi  = (u16*)  alloc((size_t)ROWS * 32 * 2);
    u16*   st_lo  = (u16*)  alloc((size_t)ROWS * 32 * 2);
    float* agg    = (float*)alloc((size_t)ROWS * 32 * 4);
    u16*   ew2f   = (u16*)  alloc(64 * 512 * 2);
    u16*   pw1h   = (u16*)  alloc(2 * 512 * 2);
    u16*   pw1l   = (u16*)  alloc(2 * 512 * 2);
    u16*   pw2h   = (u16*)  alloc(2 * 512 * 2);
    u16*   pw2l   = (u16*)  alloc(2 * 512 * 2);
    u16*   wihhf  = (u16*)  alloc(6 * 512 * 2);
    u16*   wihlf  = (u16*)  alloc(6 * 512 * 2);
    u16*   whhhf  = (u16*)  alloc(6 * 512 * 2);
    u16*   whhlf  = (u16*)  alloc(6 * 512 * 2);
    (void)in_sizes; (void)n_in; (void)out_size; (void)ws_size;

    pack_bfrag<<<128, 256, 0, stream>>>(ew2, ew2f, (u16*)nullptr, 64, 1024, 0);
    pack_bfrag<<<4,   256, 0, stream>>>(pw1, pw1h, pw1l, 2, 32, 0);
    pack_bfrag<<<4,   256, 0, stream>>>(pw2, pw2h, pw2l, 2, 32, 0);
    pack_bfrag<<<12,  256, 0, stream>>>(wih, wihhf, wihlf, 6, 96, 1);
    pack_bfrag<<<12,  256, 0, stream>>>(whh, whhhf, whhlf, 6, 96, 1);

    edgemlp_kernel<<<NEDGES / 8, 256, 0, stream>>>(er, ew1, eb1, rbf);
    nodeproj_kernel<<<ROWS / 64, 256, 0, stream>>>(x, pw1h, pw1l, pb1, pw2h, pw2l, pb2,
                                                   st_f32, st_hi, st_lo);
    for (int s = 0; s < 3; ++s) {
        hipMemsetAsync(agg, 0, (size_t)ROWS * 32 * 4, stream);
        msg_kernel<<<NEDGES / 64, 256, 0, stream>>>(rbf, ew2f, eb2, st_f32, esrc, edst, agg);
        float* of = (s == 2) ? out : st_f32;
        gru_kernel<<<ROWS / 64, 256, 0, stream>>>(agg, conv_b, st_f32, st_hi, st_lo,
                                                  wihhf, wihlf, whhhf, whhlf, bih, bhh,
                                                  of, st_hi, st_lo);
    }
}